// Round 1
// 765.499 us; speedup vs baseline: 1.0558x; 1.0558x over previous
//
#include <hip/hip_runtime.h>
#include <stdint.h>

// MFMA fragment types (guide §3: bf16 16x16x32 -> 8x short A/B, 4x float C/D)
typedef short bf16x8 __attribute__((ext_vector_type(8)));
typedef float f32x4 __attribute__((ext_vector_type(4)));

__device__ __forceinline__ float bf2f(uint16_t u) {
  union { uint32_t i; float f; } v; v.i = ((uint32_t)u) << 16; return v.f;
}
__device__ __forceinline__ uint16_t f2bf(float f) {
  union { float f; uint32_t i; } v; v.f = f;
  uint32_t x = v.i;
  return (uint16_t)((x + 0x7fffu + ((x >> 16) & 1u)) >> 16); // RNE
}

// Fused: zero(cnt,cur,gcur) for blocks [0,zb) | wcvt (build Wcat) for blocks [zb,zb+128)
__global__ void prep0_kernel(int* __restrict__ cnt, int* __restrict__ cur, int* __restrict__ gcur,
                             int N, int zb,
                             const float* __restrict__ Wl1, const float* __restrict__ Wr1,
                             const float* __restrict__ Wl2, const float* __restrict__ Wr2,
                             uint32_t* __restrict__ Wcat) {
  if ((int)blockIdx.x < zb) {
    int i = blockIdx.x * 256 + threadIdx.x;
    if (i < N) { cnt[i] = 0; cur[i] = 0; }
    if (i == 0 && blockIdx.x == 0) *gcur = 0;
  } else {
    int e = (blockIdx.x - zb) * 256 + threadIdx.x; // 2 * 128 * 128 u32 (each = 2 bf16)
    if (e >= 32768) return;
    int L = e >> 14, r = e & 16383;
    int o = r >> 7, kc = r & 127;
    const float* W = (kc < 64) ? (L ? Wl2 : Wl1) : (L ? Wr2 : Wr1);
    int k2 = (kc & 63) * 2;
    float a = W[o * 128 + k2];
    float b = W[o * 128 + k2 + 1];
    Wcat[e] = (uint32_t)f2bf(a) | ((uint32_t)f2bf(b) << 16);
  }
}

// Fused: count (degree histogram) for blocks [0,cb) | h-gather for blocks [cb,cb+gb).
// Independent work; fusing overlaps gather's HBM-latency chain with count's L2 atomics.
__global__ void count_gather_kernel(const int* __restrict__ dst, int* __restrict__ cnt, int E, int cb,
                                    const int* __restrict__ x, const float* __restrict__ emb,
                                    uint32_t* __restrict__ A, int N) {
  if ((int)blockIdx.x < cb) {
    int e = blockIdx.x * 256 + threadIdx.x;
    if (e < E) atomicAdd(&cnt[dst[e]], 1);
  } else {
    int gw = ((blockIdx.x - cb) * 256 + threadIdx.x) >> 6;
    int lane = threadIdx.x & 63;
    if (gw >= N) return;
    long row = x[gw];
    float2 v = *(const float2*)(emb + row * 128 + lane * 2);
    A[(long)gw * 128 + 64 + lane] = (uint32_t)f2bf(v.x) | ((uint32_t)f2bf(v.y) << 16);
  }
}

// Disjoint segment allocation WITHOUT a global sorted scan: per-wave exclusive
// shuffle-scan of 64 counts + ONE atomicAdd of the wave total on a global
// cursor. Order of segments in csr[] is irrelevant (mean is commutative).
__global__ void alloc_kernel(const int* __restrict__ cnt, int* __restrict__ row_start,
                             int* __restrict__ gcur, int N) {
  int i = blockIdx.x * 256 + threadIdx.x;
  int lane = threadIdx.x & 63;
  int v = (i < N) ? cnt[i] : 0;
  int x = v;
#pragma unroll
  for (int off = 1; off < 64; off <<= 1) {
    int y = __shfl_up(x, off, 64);
    if (lane >= off) x += y;
  }
  int total = __shfl(x, 63, 64);
  int base = 0;
  if (lane == 63) base = atomicAdd(gcur, total);
  base = __shfl(base, 63, 64);
  if (i < N) row_start[i] = base + x - v;  // exclusive prefix within wave
}

__global__ void fill_kernel(const int* __restrict__ src, const int* __restrict__ dst,
                            const int* __restrict__ row_start, int* __restrict__ cur,
                            int* __restrict__ csr, int E) {
  int e = blockIdx.x * 256 + threadIdx.x;
  if (e < E) {
    int d = dst[e];
    int pos = row_start[d] + atomicAdd(&cur[d], 1);
    csr[pos] = src[e];
  }
}

// Mean aggregation: reads A[:,128:256] (bf16 h), writes A[:,0:128] (bf16 agg), fp32 accum.
// One wave per node. v2: preload up to 64 neighbor indices with ONE coalesced load
// (lane l reads csr[b+l]) and broadcast via __shfl — removes the dependent
// csr-index load from the per-neighbor critical path so the A-row loads issue
// back-to-back. Accumulation order kept EXACTLY as v1 (pairwise, ascending).
__global__ void agg_kernel(uint32_t* __restrict__ A, const int* __restrict__ row_start,
                           const int* __restrict__ cnt, const int* __restrict__ csr, int N) {
  int gw = (blockIdx.x * 256 + threadIdx.x) >> 6;
  int lane = threadIdx.x & 63;
  if (gw >= N) return;
  int b = row_start[gw];
  int deg = cnt[gw];
  float ax = 0.f, ay = 0.f;
  int done = 0;
  while (done < deg) {
    int chunk = deg - done;
    if (chunk > 64) chunk = 64;
    int idx = (lane < chunk) ? csr[b + done + lane] : 0;
    int i = 0;
    for (; i + 3 < chunk; i += 4) {
      int s0 = __shfl(idx, i, 64);
      int s1 = __shfl(idx, i + 1, 64);
      int s2 = __shfl(idx, i + 2, 64);
      int s3 = __shfl(idx, i + 3, 64);
      uint32_t v0 = A[(long)s0 * 128 + 64 + lane];
      uint32_t v1 = A[(long)s1 * 128 + 64 + lane];
      uint32_t v2 = A[(long)s2 * 128 + 64 + lane];
      uint32_t v3 = A[(long)s3 * 128 + 64 + lane];
      ax += bf2f((uint16_t)(v0 & 0xffff)) + bf2f((uint16_t)(v1 & 0xffff));
      ay += bf2f((uint16_t)(v0 >> 16)) + bf2f((uint16_t)(v1 >> 16));
      ax += bf2f((uint16_t)(v2 & 0xffff)) + bf2f((uint16_t)(v3 & 0xffff));
      ay += bf2f((uint16_t)(v2 >> 16)) + bf2f((uint16_t)(v3 >> 16));
    }
    for (; i + 1 < chunk; i += 2) {
      int s0 = __shfl(idx, i, 64);
      int s1 = __shfl(idx, i + 1, 64);
      uint32_t v0 = A[(long)s0 * 128 + 64 + lane];
      uint32_t v1 = A[(long)s1 * 128 + 64 + lane];
      ax += bf2f((uint16_t)(v0 & 0xffff)) + bf2f((uint16_t)(v1 & 0xffff));
      ay += bf2f((uint16_t)(v0 >> 16)) + bf2f((uint16_t)(v1 >> 16));
    }
    if (i < chunk) {
      int s0 = __shfl(idx, i, 64);
      uint32_t v = A[(long)s0 * 128 + 64 + lane];
      ax += bf2f((uint16_t)(v & 0xffff));
      ay += bf2f((uint16_t)(v >> 16));
    }
    done += chunk;
  }
  float sc = 1.0f / (float)(deg > 0 ? deg : 1);
  A[(long)gw * 128 + lane] = (uint32_t)f2bf(ax * sc) | ((uint32_t)f2bf(ay * sc) << 16);
}

// out = relu(A[n,0:256] @ Wcat^T + bias); block tile 128(M)x128(N), K=256.
// Wave tile 64x64 = 4x4 MFMA 16x16x32 tiles. W in LDS, XOR bank-swizzled for
// conflict-free ds_read_b128 B-fragment loads. FINAL stores fp32 to d_out.
template <bool FINAL>
__global__ __launch_bounds__(256) void gemm_kernel(const uint16_t* __restrict__ A,
                                                   const uint32_t* __restrict__ Wcat,
                                                   const float* __restrict__ bias,
                                                   uint16_t* __restrict__ outH, // A2 base (bf16 h-part)
                                                   float* __restrict__ outF,    // d_out fp32 [N][128]
                                                   int N) {
  __shared__ uint32_t lds[16384]; // 64 KiB: W as [o][kc] u32, group-swizzled
  for (int e = threadIdx.x; e < 16384; e += 256) {
    int o = e >> 7, kc = e & 127;
    int g = kc >> 2, c = kc & 3;
    lds[(o << 7) | ((g ^ (o & 7)) << 2) | c] = Wcat[e];
  }
  __syncthreads();
  int lane = threadIdx.x & 63, wv = threadIdx.x >> 6;
  int wm = wv >> 1, wo = wv & 1;
  int ol = lane & 15, q = lane >> 4;
  int nb = blockIdx.x * 128 + wm * 64;
  f32x4 acc[4][4] = {};
#pragma unroll
  for (int ks = 0; ks < 8; ks++) {
    bf16x8 a[4], bfr[4];
#pragma unroll
    for (int mt = 0; mt < 4; mt++) {
      long n = nb + mt * 16 + ol;
      a[mt] = *(const bf16x8*)(A + n * 256 + ks * 32 + q * 8);
    }
#pragma unroll
    for (int ot = 0; ot < 4; ot++) {
      int o = wo * 64 + ot * 16 + ol;
      int g = ks * 4 + q;
      bfr[ot] = *(const bf16x8*)&lds[(o << 7) | ((g ^ (o & 7)) << 2)];
    }
#pragma unroll
    for (int mt = 0; mt < 4; mt++)
#pragma unroll
      for (int ot = 0; ot < 4; ot++)
        acc[mt][ot] = __builtin_amdgcn_mfma_f32_16x16x32_bf16(a[mt], bfr[ot], acc[mt][ot], 0, 0, 0);
  }
  // C/D layout: col(=o) = lane&15, row(=node) = (lane>>4)*4 + reg
#pragma unroll
  for (int ot = 0; ot < 4; ot++) {
    int o = wo * 64 + ot * 16 + ol;
    float bv = bias[o];
#pragma unroll
    for (int mt = 0; mt < 4; mt++) {
#pragma unroll
      for (int r = 0; r < 4; r++) {
        int n = nb + mt * 16 + q * 4 + r;
        if (n < N) {
          float v = acc[mt][ot][r] + bv;
          v = v > 0.f ? v : 0.f;
          if (FINAL) outF[(long)n * 128 + o] = v;
          else outH[(long)n * 256 + 128 + o] = f2bf(v);
        }
      }
    }
  }
}

extern "C" void kernel_launch(void* const* d_in, const int* in_sizes, int n_in,
                              void* d_out, int out_size, void* d_ws, size_t ws_size,
                              hipStream_t stream) {
  const int* x = (const int*)d_in[0];
  const int* edge = (const int*)d_in[1];
  const float* emb = (const float*)d_in[2];
  const float* W1l = (const float*)d_in[3];
  const float* b1 = (const float*)d_in[4];
  const float* W1r = (const float*)d_in[5];
  const float* W2l = (const float*)d_in[6];
  const float* b2 = (const float*)d_in[7];
  const float* W2r = (const float*)d_in[8];
  const int N = in_sizes[0];
  const int E = in_sizes[1] / 2;
  const int* srcE = edge;
  const int* dstE = edge + E;

  const int Npad = ((N + 127) / 128) * 128;
  char* p = (char*)d_ws;
  uint16_t* A1 = (uint16_t*)p; p += (size_t)Npad * 256 * 2;  // [Npad][256] bf16: [agg | h]
  uint16_t* A2 = (uint16_t*)p; p += (size_t)Npad * 256 * 2;
  uint32_t* Wcat = (uint32_t*)p; p += (size_t)2 * 16384 * 4;
  int* cnt = (int*)p;       p += (((size_t)N * 4 + 255) / 256) * 256;
  int* cur = (int*)p;       p += (((size_t)N * 4 + 255) / 256) * 256;
  int* row_start = (int*)p; p += (((size_t)N * 4 + 255) / 256) * 256;
  int* csr = (int*)p;       p += (((size_t)E * 4 + 255) / 256) * 256;
  int* gcur = (int*)p;      p += 256;

  const int zb = (N + 255) / 256;       // zero blocks
  const int cb = (E + 255) / 256;       // count blocks
  const int gb = (N + 3) / 4;           // gather blocks (4 waves/block)

  prep0_kernel<<<zb + 128, 256, 0, stream>>>(cnt, cur, gcur, N, zb, W1l, W1r, W2l, W2r, Wcat);
  count_gather_kernel<<<cb + gb, 256, 0, stream>>>(dstE, cnt, E, cb, x, emb, (uint32_t*)A1, N);
  alloc_kernel<<<(N + 255) / 256, 256, 0, stream>>>(cnt, row_start, gcur, N);
  fill_kernel<<<(E + 255) / 256, 256, 0, stream>>>(srcE, dstE, row_start, cur, csr, E);
  agg_kernel<<<(N + 3) / 4, 256, 0, stream>>>((uint32_t*)A1, row_start, cnt, csr, N);
  gemm_kernel<false><<<Npad / 128, 256, 0, stream>>>(A1, Wcat, b1, A2, nullptr, N);
  agg_kernel<<<(N + 3) / 4, 256, 0, stream>>>((uint32_t*)A2, row_start, cnt, csr, N);
  gemm_kernel<true><<<Npad / 128, 256, 0, stream>>>(A2, Wcat + 16384, b2, nullptr, (float*)d_out, N);
}

// Round 2
// 764.150 us; speedup vs baseline: 1.0576x; 1.0018x over previous
//
#include <hip/hip_runtime.h>
#include <stdint.h>

// MFMA fragment types (guide §3: bf16 16x16x32 -> 8x short A/B, 4x float C/D)
typedef short bf16x8 __attribute__((ext_vector_type(8)));
typedef float f32x4 __attribute__((ext_vector_type(4)));

__device__ __forceinline__ float bf2f(uint16_t u) {
  union { uint32_t i; float f; } v; v.i = ((uint32_t)u) << 16; return v.f;
}
__device__ __forceinline__ uint16_t f2bf(float f) {
  union { float f; uint32_t i; } v; v.f = f;
  uint32_t x = v.i;
  return (uint16_t)((x + 0x7fffu + ((x >> 16) & 1u)) >> 16); // RNE
}

// Fused: zero(cnt,cur,gcur) for blocks [0,zb) | wcvt (build Wcat) for blocks [zb,zb+128)
__global__ void prep0_kernel(int* __restrict__ cnt, int* __restrict__ cur, int* __restrict__ gcur,
                             int N, int zb,
                             const float* __restrict__ Wl1, const float* __restrict__ Wr1,
                             const float* __restrict__ Wl2, const float* __restrict__ Wr2,
                             uint32_t* __restrict__ Wcat) {
  if ((int)blockIdx.x < zb) {
    int i = blockIdx.x * 256 + threadIdx.x;
    if (i < N) { cnt[i] = 0; cur[i] = 0; }
    if (i == 0 && blockIdx.x == 0) *gcur = 0;
  } else {
    int e = (blockIdx.x - zb) * 256 + threadIdx.x; // 2 * 128 * 128 u32 (each = 2 bf16)
    if (e >= 32768) return;
    int L = e >> 14, r = e & 16383;
    int o = r >> 7, kc = r & 127;
    const float* W = (kc < 64) ? (L ? Wl2 : Wl1) : (L ? Wr2 : Wr1);
    int k2 = (kc & 63) * 2;
    float a = W[o * 128 + k2];
    float b = W[o * 128 + k2 + 1];
    Wcat[e] = (uint32_t)f2bf(a) | ((uint32_t)f2bf(b) << 16);
  }
}

// Fused: count (degree histogram) for blocks [0,cb) | h-gather for blocks [cb,cb+gb).
__global__ void count_gather_kernel(const int* __restrict__ dst, int* __restrict__ cnt, int E, int cb,
                                    const int* __restrict__ x, const float* __restrict__ emb,
                                    uint32_t* __restrict__ A, int N) {
  if ((int)blockIdx.x < cb) {
    int e = blockIdx.x * 256 + threadIdx.x;
    if (e < E) atomicAdd(&cnt[dst[e]], 1);
  } else {
    int gw = ((blockIdx.x - cb) * 256 + threadIdx.x) >> 6;
    int lane = threadIdx.x & 63;
    if (gw >= N) return;
    long row = x[gw];
    float2 v = *(const float2*)(emb + row * 128 + lane * 2);
    A[(long)gw * 128 + 64 + lane] = (uint32_t)f2bf(v.x) | ((uint32_t)f2bf(v.y) << 16);
  }
}

// Per-wave exclusive shuffle-scan of 64 counts + ONE atomicAdd of the wave total.
__global__ void alloc_kernel(const int* __restrict__ cnt, int* __restrict__ row_start,
                             int* __restrict__ gcur, int N) {
  int i = blockIdx.x * 256 + threadIdx.x;
  int lane = threadIdx.x & 63;
  int v = (i < N) ? cnt[i] : 0;
  int x = v;
#pragma unroll
  for (int off = 1; off < 64; off <<= 1) {
    int y = __shfl_up(x, off, 64);
    if (lane >= off) x += y;
  }
  int total = __shfl(x, 63, 64);
  int base = 0;
  if (lane == 63) base = atomicAdd(gcur, total);
  base = __shfl(base, 63, 64);
  if (i < N) row_start[i] = base + x - v;  // exclusive prefix within wave
}

__global__ void fill_kernel(const int* __restrict__ src, const int* __restrict__ dst,
                            const int* __restrict__ row_start, int* __restrict__ cur,
                            int* __restrict__ csr, int E) {
  int e = blockIdx.x * 256 + threadIdx.x;
  if (e < E) {
    int d = dst[e];
    int pos = row_start[d] + atomicAdd(&cur[d], 1);
    csr[pos] = src[e];
  }
}

// Mean aggregation: reads A[:,128:256] (bf16 h), writes A[:,0:128] (bf16 agg), fp32 accum.
// One wave per node. v3: coalesced 64-wide csr preload + __shfl broadcast, with up to
// EIGHT A-row loads in flight (deepened from 4; L3 round-trip ~400-600cy, row loads
// are independent). Accumulation order kept EXACTLY pairwise-ascending (bit-identical).
__global__ void agg_kernel(uint32_t* __restrict__ A, const int* __restrict__ row_start,
                           const int* __restrict__ cnt, const int* __restrict__ csr, int N) {
  int gw = (blockIdx.x * 256 + threadIdx.x) >> 6;
  int lane = threadIdx.x & 63;
  if (gw >= N) return;
  int b = row_start[gw];
  int deg = cnt[gw];
  const uint32_t* Ah = A + 64 + lane;
  float ax = 0.f, ay = 0.f;
  int done = 0;
  while (done < deg) {
    int chunk = deg - done;
    if (chunk > 64) chunk = 64;
    int idx = (lane < chunk) ? csr[b + done + lane] : 0;
    int i = 0;
    for (; i + 7 < chunk; i += 8) {
      int s0 = __shfl(idx, i, 64);
      int s1 = __shfl(idx, i + 1, 64);
      int s2 = __shfl(idx, i + 2, 64);
      int s3 = __shfl(idx, i + 3, 64);
      int s4 = __shfl(idx, i + 4, 64);
      int s5 = __shfl(idx, i + 5, 64);
      int s6 = __shfl(idx, i + 6, 64);
      int s7 = __shfl(idx, i + 7, 64);
      uint32_t v0 = Ah[(long)s0 * 128];
      uint32_t v1 = Ah[(long)s1 * 128];
      uint32_t v2 = Ah[(long)s2 * 128];
      uint32_t v3 = Ah[(long)s3 * 128];
      uint32_t v4 = Ah[(long)s4 * 128];
      uint32_t v5 = Ah[(long)s5 * 128];
      uint32_t v6 = Ah[(long)s6 * 128];
      uint32_t v7 = Ah[(long)s7 * 128];
      ax += bf2f((uint16_t)(v0 & 0xffff)) + bf2f((uint16_t)(v1 & 0xffff));
      ay += bf2f((uint16_t)(v0 >> 16)) + bf2f((uint16_t)(v1 >> 16));
      ax += bf2f((uint16_t)(v2 & 0xffff)) + bf2f((uint16_t)(v3 & 0xffff));
      ay += bf2f((uint16_t)(v2 >> 16)) + bf2f((uint16_t)(v3 >> 16));
      ax += bf2f((uint16_t)(v4 & 0xffff)) + bf2f((uint16_t)(v5 & 0xffff));
      ay += bf2f((uint16_t)(v4 >> 16)) + bf2f((uint16_t)(v5 >> 16));
      ax += bf2f((uint16_t)(v6 & 0xffff)) + bf2f((uint16_t)(v7 & 0xffff));
      ay += bf2f((uint16_t)(v6 >> 16)) + bf2f((uint16_t)(v7 >> 16));
    }
    for (; i + 3 < chunk; i += 4) {
      int s0 = __shfl(idx, i, 64);
      int s1 = __shfl(idx, i + 1, 64);
      int s2 = __shfl(idx, i + 2, 64);
      int s3 = __shfl(idx, i + 3, 64);
      uint32_t v0 = Ah[(long)s0 * 128];
      uint32_t v1 = Ah[(long)s1 * 128];
      uint32_t v2 = Ah[(long)s2 * 128];
      uint32_t v3 = Ah[(long)s3 * 128];
      ax += bf2f((uint16_t)(v0 & 0xffff)) + bf2f((uint16_t)(v1 & 0xffff));
      ay += bf2f((uint16_t)(v0 >> 16)) + bf2f((uint16_t)(v1 >> 16));
      ax += bf2f((uint16_t)(v2 & 0xffff)) + bf2f((uint16_t)(v3 & 0xffff));
      ay += bf2f((uint16_t)(v2 >> 16)) + bf2f((uint16_t)(v3 >> 16));
    }
    for (; i + 1 < chunk; i += 2) {
      int s0 = __shfl(idx, i, 64);
      int s1 = __shfl(idx, i + 1, 64);
      uint32_t v0 = Ah[(long)s0 * 128];
      uint32_t v1 = Ah[(long)s1 * 128];
      ax += bf2f((uint16_t)(v0 & 0xffff)) + bf2f((uint16_t)(v1 & 0xffff));
      ay += bf2f((uint16_t)(v0 >> 16)) + bf2f((uint16_t)(v1 >> 16));
    }
    if (i < chunk) {
      int s0 = __shfl(idx, i, 64);
      uint32_t v = Ah[(long)s0 * 128];
      ax += bf2f((uint16_t)(v & 0xffff));
      ay += bf2f((uint16_t)(v >> 16));
    }
    done += chunk;
  }
  float sc = 1.0f / (float)(deg > 0 ? deg : 1);
  A[(long)gw * 128 + lane] = (uint32_t)f2bf(ax * sc) | ((uint32_t)f2bf(ay * sc) << 16);
}

// out = relu(A[n,0:256] @ Wcat^T + bias); block tile 128(M)x128(N), K=256.
// v2: NO LDS. Wcat is 64 KiB/layer and read by every block -> guaranteed L2-resident.
// B fragments load directly from global: per wave instruction, 16 rows x 64 B
// contiguous (full line utilization), overlapped with MFMA by the scheduler.
// Removes 64 staged global+ds_write iterations/thread, the barrier, and all LDS.
template <bool FINAL>
__global__ __launch_bounds__(256) void gemm_kernel(const uint16_t* __restrict__ A,
                                                   const uint16_t* __restrict__ Wcat, // [128][256] bf16
                                                   const float* __restrict__ bias,
                                                   uint16_t* __restrict__ outH, // A2 base (bf16 h-part)
                                                   float* __restrict__ outF,    // d_out fp32 [N][128]
                                                   int N) {
  int lane = threadIdx.x & 63, wv = threadIdx.x >> 6;
  int wm = wv >> 1, wo = wv & 1;
  int ol = lane & 15, q = lane >> 4;
  int nb = blockIdx.x * 128 + wm * 64;
  f32x4 acc[4][4] = {};
#pragma unroll
  for (int ks = 0; ks < 8; ks++) {
    bf16x8 a[4], bfr[4];
#pragma unroll
    for (int mt = 0; mt < 4; mt++) {
      long n = nb + mt * 16 + ol;
      a[mt] = *(const bf16x8*)(A + n * 256 + ks * 32 + q * 8);
    }
#pragma unroll
    for (int ot = 0; ot < 4; ot++) {
      int o = wo * 64 + ot * 16 + ol;
      bfr[ot] = *(const bf16x8*)(Wcat + o * 256 + ks * 32 + q * 8);
    }
#pragma unroll
    for (int mt = 0; mt < 4; mt++)
#pragma unroll
      for (int ot = 0; ot < 4; ot++)
        acc[mt][ot] = __builtin_amdgcn_mfma_f32_16x16x32_bf16(a[mt], bfr[ot], acc[mt][ot], 0, 0, 0);
  }
  // C/D layout: col(=o) = lane&15, row(=node) = (lane>>4)*4 + reg
#pragma unroll
  for (int ot = 0; ot < 4; ot++) {
    int o = wo * 64 + ot * 16 + ol;
    float bv = bias[o];
#pragma unroll
    for (int mt = 0; mt < 4; mt++) {
#pragma unroll
      for (int r = 0; r < 4; r++) {
        int n = nb + mt * 16 + q * 4 + r;
        if (n < N) {
          float v = acc[mt][ot][r] + bv;
          v = v > 0.f ? v : 0.f;
          if (FINAL) outF[(long)n * 128 + o] = v;
          else outH[(long)n * 256 + 128 + o] = f2bf(v);
        }
      }
    }
  }
}

extern "C" void kernel_launch(void* const* d_in, const int* in_sizes, int n_in,
                              void* d_out, int out_size, void* d_ws, size_t ws_size,
                              hipStream_t stream) {
  const int* x = (const int*)d_in[0];
  const int* edge = (const int*)d_in[1];
  const float* emb = (const float*)d_in[2];
  const float* W1l = (const float*)d_in[3];
  const float* b1 = (const float*)d_in[4];
  const float* W1r = (const float*)d_in[5];
  const float* W2l = (const float*)d_in[6];
  const float* b2 = (const float*)d_in[7];
  const float* W2r = (const float*)d_in[8];
  const int N = in_sizes[0];
  const int E = in_sizes[1] / 2;
  const int* srcE = edge;
  const int* dstE = edge + E;

  const int Npad = ((N + 127) / 128) * 128;
  char* p = (char*)d_ws;
  uint16_t* A1 = (uint16_t*)p; p += (size_t)Npad * 256 * 2;  // [Npad][256] bf16: [agg | h]
  uint16_t* A2 = (uint16_t*)p; p += (size_t)Npad * 256 * 2;
  uint32_t* Wcat = (uint32_t*)p; p += (size_t)2 * 16384 * 4;
  int* cnt = (int*)p;       p += (((size_t)N * 4 + 255) / 256) * 256;
  int* cur = (int*)p;       p += (((size_t)N * 4 + 255) / 256) * 256;
  int* row_start = (int*)p; p += (((size_t)N * 4 + 255) / 256) * 256;
  int* csr = (int*)p;       p += (((size_t)E * 4 + 255) / 256) * 256;
  int* gcur = (int*)p;      p += 256;

  const int zb = (N + 255) / 256;       // zero blocks
  const int cb = (E + 255) / 256;       // count blocks
  const int gb = (N + 3) / 4;           // gather blocks (4 waves/block)

  prep0_kernel<<<zb + 128, 256, 0, stream>>>(cnt, cur, gcur, N, zb, W1l, W1r, W2l, W2r, Wcat);
  count_gather_kernel<<<cb + gb, 256, 0, stream>>>(dstE, cnt, E, cb, x, emb, (uint32_t*)A1, N);
  alloc_kernel<<<(N + 255) / 256, 256, 0, stream>>>(cnt, row_start, gcur, N);
  fill_kernel<<<(E + 255) / 256, 256, 0, stream>>>(srcE, dstE, row_start, cur, csr, E);
  agg_kernel<<<(N + 3) / 4, 256, 0, stream>>>((uint32_t*)A1, row_start, cnt, csr, N);
  gemm_kernel<false><<<Npad / 128, 256, 0, stream>>>(A1, (const uint16_t*)Wcat, b1, A2, nullptr, N);
  agg_kernel<<<(N + 3) / 4, 256, 0, stream>>>((uint32_t*)A2, row_start, cnt, csr, N);
  gemm_kernel<true><<<Npad / 128, 256, 0, stream>>>(A2, (const uint16_t*)(Wcat + 16384), b2, nullptr, (float*)d_out, N);
}